// Round 5
// baseline (171.681 us; speedup 1.0000x reference)
//
#include <hip/hip_runtime.h>
#include <hip/hip_bf16.h>
#include <stdint.h>

#define BDIM 4096
#define DDIM 1024
#define KSEL 1024
#define MARGINF 0.5f
#define EPSF 1e-6f

typedef __attribute__((ext_vector_type(8))) short short8v;
typedef __attribute__((ext_vector_type(4))) float float4v;

// ---------------- helpers ----------------

__device__ __forceinline__ unsigned short f2bf(float f) {
  uint32_t u = __float_as_uint(f);
  uint32_t r = (u + 0x7FFFu + ((u >> 16) & 1u)) >> 16;
  return (unsigned short)r;
}

__device__ __forceinline__ float bf2f(unsigned short u) {
  return __uint_as_float((uint32_t)u << 16);
}

__device__ __forceinline__ void gload_lds16(const void* g, void* l) {
  __builtin_amdgcn_global_load_lds(
      (const __attribute__((address_space(1))) void*)g,
      (__attribute__((address_space(3))) void*)l, 16, 0, 0);
}

// ---------------- prep: fp32 -> bf16, norms, and exact-pipeline posv ------
// one wave per row pair (x_i, y_i)
__global__ __launch_bounds__(256) void prep_kernel(
    const float* __restrict__ x, const float* __restrict__ y,
    unsigned short* __restrict__ xbf, unsigned short* __restrict__ ybf,
    float* __restrict__ xn, float* __restrict__ yn,
    float* __restrict__ posv) {
  int wv = threadIdx.x >> 6, lane = threadIdx.x & 63;
  int row = blockIdx.x * 4 + wv;  // 0..4095
  const float* xp = x + (size_t)row * DDIM;
  const float* yp = y + (size_t)row * DDIM;
  unsigned short* xo = xbf + (size_t)row * DDIM;
  unsigned short* yo = ybf + (size_t)row * DDIM;
  float sxx = 0.f, syy = 0.f, sxy = 0.f;
#pragma unroll
  for (int it = 0; it < 4; ++it) {
    int k = it * 256 + lane * 4;
    float4 xv = *reinterpret_cast<const float4*>(xp + k);
    float4 yv = *reinterpret_cast<const float4*>(yp + k);
    xv.x += EPSF; xv.y += EPSF; xv.z += EPSF; xv.w += EPSF;
    sxx += xv.x * xv.x + xv.y * xv.y + xv.z * xv.z + xv.w * xv.w;
    syy += yv.x * yv.x + yv.y * yv.y + yv.z * yv.z + yv.w * yv.w;
    ushort4 xq, yq;
    xq.x = f2bf(xv.x); xq.y = f2bf(xv.y); xq.z = f2bf(xv.z); xq.w = f2bf(xv.w);
    yq.x = f2bf(yv.x); yq.y = f2bf(yv.y); yq.z = f2bf(yv.z); yq.w = f2bf(yv.w);
    // xy dot on the bf16-rounded values (matches the MFMA dist pipeline)
    sxy += bf2f(xq.x) * bf2f(yq.x) + bf2f(xq.y) * bf2f(yq.y) +
           bf2f(xq.z) * bf2f(yq.z) + bf2f(xq.w) * bf2f(yq.w);
    *reinterpret_cast<ushort4*>(xo + k) = xq;
    *reinterpret_cast<ushort4*>(yo + k) = yq;
  }
#pragma unroll
  for (int off = 32; off > 0; off >>= 1) {
    sxx += __shfl_down(sxx, off);
    syy += __shfl_down(syy, off);
    sxy += __shfl_down(sxy, off);
  }
  if (lane == 0) {
    xn[row] = sxx;
    yn[row] = syy;
    posv[row] = sqrtf(fmaxf(sxx + syy - 2.f * sxy, 0.f));
  }
}

// ---------------- GEMM + distance epilogue (BK=64, swizzled LDS) ----------
// 128x128 tile, BK=64, 4 waves (2x2). LDS staging chunk-XOR swizzled via
// pre-swizzled GLOBAL source (linear global_load_lds dest) + swizzled reads.
// Epilogue stages the bf16 tile in LDS (transposed layout) and writes both
// dist and distT as full-line coalesced 128B-per-thread stores.
__global__ __launch_bounds__(256) void gemm_dist_kernel(
    const unsigned short* __restrict__ Xb, const unsigned short* __restrict__ Yb,
    const float* __restrict__ xn, const float* __restrict__ yn,
    unsigned short* __restrict__ dist, unsigned short* __restrict__ distT) {
  __shared__ unsigned short smem[128 * 128];  // 32 KB: As|Bs, then tile_T
  unsigned short* As = smem;                  // [128][64]
  unsigned short* Bs = smem + 128 * 64;

  int tid = threadIdx.x;
  int lane = tid & 63, w = tid >> 6;
  int wr = w >> 1, wc = w & 1;
  // XCD-aware swizzle over the 32x32 grid (1024 wgs, 1024%8==0 -> bijective)
  int wg = blockIdx.y * 32 + blockIdx.x;
  int swz = (wg & 7) * 128 + (wg >> 3);
  int brow = (swz >> 5) * 128, bcol = (swz & 31) * 128;

  float4v acc[4][4];
#pragma unroll
  for (int m = 0; m < 4; ++m)
#pragma unroll
    for (int n = 0; n < 4; ++n) acc[m][n] = (float4v){0.f, 0.f, 0.f, 0.f};

  int srow8 = lane >> 3;            // 0..7: row within 8-row chunk
  int sc16 = (lane & 7) ^ srow8;    // pre-swizzled 16B-chunk index

  for (int kt = 0; kt < DDIM / 64; ++kt) {
#pragma unroll
    for (int it = 0; it < 4; ++it) {
      int q = w * 4 + it;           // 0..15: 8-row chunk
      int rb = q * 8;
      const unsigned short* gp =
          Xb + (size_t)(brow + rb + srow8) * DDIM + kt * 64 + sc16 * 8;
      gload_lds16(gp, As + rb * 64);
      const unsigned short* gq =
          Yb + (size_t)(bcol + rb + srow8) * DDIM + kt * 64 + sc16 * 8;
      gload_lds16(gq, Bs + rb * 64);
    }
    __syncthreads();
#pragma unroll
    for (int ks = 0; ks < 2; ++ks) {
      short8v a[4], b[4];
#pragma unroll
      for (int m = 0; m < 4; ++m) {
        int row = wr * 64 + m * 16 + (lane & 15);
        int ch = (ks * 4 + (lane >> 4)) ^ (row & 7);
        a[m] = *reinterpret_cast<const short8v*>(As + row * 64 + ch * 8);
      }
#pragma unroll
      for (int n = 0; n < 4; ++n) {
        int row = wc * 64 + n * 16 + (lane & 15);
        int ch = (ks * 4 + (lane >> 4)) ^ (row & 7);
        b[n] = *reinterpret_cast<const short8v*>(Bs + row * 64 + ch * 8);
      }
#pragma unroll
      for (int m = 0; m < 4; ++m)
#pragma unroll
        for (int n = 0; n < 4; ++n)
          acc[m][n] = __builtin_amdgcn_mfma_f32_16x16x32_bf16(
              a[m], b[n], acc[m][n], 0, 0, 0);
    }
    __syncthreads();
  }

  // ---- epilogue: d into LDS tile_T[c][r] (8B-chunk XOR swizzle) ----
#pragma unroll
  for (int m = 0; m < 4; ++m) {
    int r0 = wr * 64 + m * 16 + (lane >> 4) * 4;
#pragma unroll
    for (int n = 0; n < 4; ++n) {
      int c = wc * 64 + n * 16 + (lane & 15);
      float yv = yn[bcol + c];
      ushort4 st;
      unsigned short* sp = reinterpret_cast<unsigned short*>(&st);
#pragma unroll
      for (int j = 0; j < 4; ++j) {
        float sq = xn[brow + r0 + j] + yv - 2.0f * acc[m][n][j];
        sp[j] = f2bf(sqrtf(fmaxf(sq, 0.f)));
      }
      int phys = (r0 >> 2) ^ (c & 15);
      *reinterpret_cast<uint2*>(smem + c * 128 + phys * 4) =
          *reinterpret_cast<uint2*>(&st);
    }
  }
  __syncthreads();

  // pass T: distT rows, 128B contiguous per thread
  {
    int c = tid >> 1, half = tid & 1;
    alignas(16) uint2 buf[16];
#pragma unroll
    for (int i = 0; i < 16; ++i) {
      int rc = half * 16 + i;
      int phys = rc ^ (c & 15);
      buf[i] = *reinterpret_cast<const uint2*>(smem + c * 128 + phys * 4);
    }
    unsigned short* gout = distT + (size_t)(bcol + c) * BDIM + brow + half * 64;
    const uint4* b4 = reinterpret_cast<const uint4*>(buf);
#pragma unroll
    for (int j = 0; j < 8; ++j)
      *reinterpret_cast<uint4*>(gout + j * 8) = b4[j];
  }
  // pass R: dist rows via transposed LDS reads, 128B contiguous per thread
  {
    int r = tid >> 1, half = tid & 1;
    alignas(16) unsigned short buf[64];
#pragma unroll
    for (int i = 0; i < 64; ++i) {
      int c = half * 64 + i;
      int phys = (r >> 2) ^ (c & 15);
      buf[i] = smem[c * 128 + phys * 4 + (r & 3)];
    }
    unsigned short* gout = dist + (size_t)(brow + r) * BDIM + bcol + half * 64;
    const uint4* b4 = reinterpret_cast<const uint4*>(buf);
#pragma unroll
    for (int j = 0; j < 8; ++j)
      *reinterpret_cast<uint4*>(gout + j * 8) = b4[j];
  }
}

// ---------------- per-row exact top-K-smallest hinge sum (bf16 keys) ------
__global__ __launch_bounds__(256, 4) void select_kernel(
    const unsigned short* __restrict__ dist,
    const unsigned short* __restrict__ distT,
    const float* __restrict__ posv,
    float* __restrict__ rxy, float* __restrict__ ryx) {
  int lane = threadIdx.x & 63, w = threadIdx.x >> 6;
  int r = blockIdx.x * 4 + w;           // 0..8191
  int rr = (r < BDIM) ? r : r - BDIM;
  const unsigned short* rowp =
      ((r < BDIM) ? dist : distT) + (size_t)rr * BDIM;
  float pos = posv[rr];

  uint32_t key[64];
  uint32_t kmin = 0xFFFFu, kmax = 0u;
#pragma unroll
  for (int i = 0; i < 8; ++i) {
    int idx0 = i * 512 + lane * 8;
    uint4 v = *reinterpret_cast<const uint4*>(rowp + idx0);
    uint32_t pk[4] = {v.x, v.y, v.z, v.w};
#pragma unroll
    for (int p = 0; p < 4; ++p) {
      uint32_t lo = pk[p] & 0xFFFFu, hi = pk[p] >> 16;
      kmin = min(kmin, min(lo, hi));
      kmax = max(kmax, max(lo, hi));
      int idx = idx0 + p * 2;
      key[i * 8 + p * 2 + 0] = (idx + 0 == rr) ? 0xFFFFu : lo;
      key[i * 8 + p * 2 + 1] = (idx + 1 == rr) ? 0xFFFFu : hi;
    }
  }
#pragma unroll
  for (int off = 32; off > 0; off >>= 1) {
    kmin = min(kmin, (uint32_t)__shfl_xor((int)kmin, off));
    kmax = max(kmax, (uint32_t)__shfl_xor((int)kmax, off));
  }

  uint32_t a = kmin, b = kmax;
  uint32_t T;
  bool found = false;
  while (a < b) {
    uint32_t m = (a + b) >> 1;
    int c = 0;
#pragma unroll
    for (int i = 0; i < 64; ++i) c += __popcll(__ballot(key[i] <= m));
    if (c == KSEL) { T = m; found = true; break; }
    if (c > KSEL) b = m; else a = m + 1;
  }
  if (!found) T = a;

  float Tf = __uint_as_float(T << 16);
  float pm = MARGINF + pos;
  float local = 0.f;
  int cnt_less = 0;
#pragma unroll
  for (int i = 0; i < 64; ++i) {
    uint32_t k = key[i];
    cnt_less += __popcll(__ballot(k < T));
    float d = __uint_as_float(k << 16);
    local += (k < T) ? fmaxf(pm - d, 0.f) : 0.f;
  }
#pragma unroll
  for (int off = 32; off > 0; off >>= 1) local += __shfl_xor(local, off);
  if (lane == 0) {
    float loss = local + (float)(KSEL - cnt_less) * fmaxf(pm - Tf, 0.f);
    if (r < BDIM) rxy[rr] = loss; else ryx[rr] = loss;
  }
}

// ---------------- final reduction ----------------
__global__ void finalize_kernel(const float* __restrict__ rxy,
                                const float* __restrict__ ryx,
                                float* __restrict__ out) {
  const float* src = (blockIdx.x == 0) ? rxy : ryx;
  int tid = threadIdx.x;
  double local = 0.0;
  for (int i = tid; i < BDIM; i += 256) local += (double)src[i];
  int lane = tid & 63, w = tid >> 6;
#pragma unroll
  for (int off = 32; off > 0; off >>= 1) local += __shfl_down(local, off);
  __shared__ double wsd[4];
  if (lane == 0) wsd[w] = local;
  __syncthreads();
  if (tid == 0) {
    double s = wsd[0] + wsd[1] + wsd[2] + wsd[3];
    out[blockIdx.x] = (float)(s / ((double)BDIM * (double)KSEL));
  }
}

// ---------------- launch ----------------
extern "C" void kernel_launch(void* const* d_in, const int* in_sizes, int n_in,
                              void* d_out, int out_size, void* d_ws,
                              size_t ws_size, hipStream_t stream) {
  const float* x = (const float*)d_in[0];
  const float* y = (const float*)d_in[1];
  float* out = (float*)d_out;

  char* ws = (char*)d_ws;
  size_t o = 0;
  auto take = [&](size_t bytes) -> void* {
    void* p = (void*)(ws + o);
    o += (bytes + 255) & ~(size_t)255;
    return p;
  };
  unsigned short* xbf = (unsigned short*)take((size_t)BDIM * DDIM * 2);
  unsigned short* ybf = (unsigned short*)take((size_t)BDIM * DDIM * 2);
  float* xn = (float*)take((size_t)BDIM * 4);
  float* yn = (float*)take((size_t)BDIM * 4);
  float* rxy = (float*)take((size_t)BDIM * 4);
  float* ryx = (float*)take((size_t)BDIM * 4);
  float* posv = (float*)take((size_t)BDIM * 4);
  unsigned short* dist = (unsigned short*)take((size_t)BDIM * BDIM * 2);
  unsigned short* distT = (unsigned short*)take((size_t)BDIM * BDIM * 2);

  prep_kernel<<<BDIM / 4, 256, 0, stream>>>(x, y, xbf, ybf, xn, yn, posv);
  gemm_dist_kernel<<<dim3(32, 32), 256, 0, stream>>>(xbf, ybf, xn, yn, dist,
                                                     distT);
  select_kernel<<<2 * BDIM / 4, 256, 0, stream>>>(dist, distT, posv, rxy, ryx);
  finalize_kernel<<<2, 256, 0, stream>>>(rxy, ryx, out);
}

// Round 6
// 166.993 us; speedup vs baseline: 1.0281x; 1.0281x over previous
//
#include <hip/hip_runtime.h>
#include <hip/hip_bf16.h>
#include <stdint.h>

#define BDIM 4096
#define DDIM 1024
#define KSEL 1024
#define MARGINF 0.5f
#define EPSF 1e-6f
#define NT 16  // K-tiles of 64

typedef __attribute__((ext_vector_type(8))) short short8v;
typedef __attribute__((ext_vector_type(4))) float float4v;

// ---------------- helpers ----------------

__device__ __forceinline__ unsigned short f2bf(float f) {
  uint32_t u = __float_as_uint(f);
  uint32_t r = (u + 0x7FFFu + ((u >> 16) & 1u)) >> 16;
  return (unsigned short)r;
}

__device__ __forceinline__ float bf2f(unsigned short u) {
  return __uint_as_float((uint32_t)u << 16);
}

__device__ __forceinline__ void gload_lds16(const void* g, void* l) {
  __builtin_amdgcn_global_load_lds(
      (const __attribute__((address_space(1))) void*)g,
      (__attribute__((address_space(3))) void*)l, 16, 0, 0);
}

// ---------------- prep: fp32 -> bf16, norms, and exact-pipeline posv ------
__global__ __launch_bounds__(256) void prep_kernel(
    const float* __restrict__ x, const float* __restrict__ y,
    unsigned short* __restrict__ xbf, unsigned short* __restrict__ ybf,
    float* __restrict__ xn, float* __restrict__ yn,
    float* __restrict__ posv) {
  int wv = threadIdx.x >> 6, lane = threadIdx.x & 63;
  int row = blockIdx.x * 4 + wv;  // 0..4095
  const float* xp = x + (size_t)row * DDIM;
  const float* yp = y + (size_t)row * DDIM;
  unsigned short* xo = xbf + (size_t)row * DDIM;
  unsigned short* yo = ybf + (size_t)row * DDIM;
  float sxx = 0.f, syy = 0.f, sxy = 0.f;
#pragma unroll
  for (int it = 0; it < 4; ++it) {
    int k = it * 256 + lane * 4;
    float4 xv = *reinterpret_cast<const float4*>(xp + k);
    float4 yv = *reinterpret_cast<const float4*>(yp + k);
    xv.x += EPSF; xv.y += EPSF; xv.z += EPSF; xv.w += EPSF;
    sxx += xv.x * xv.x + xv.y * xv.y + xv.z * xv.z + xv.w * xv.w;
    syy += yv.x * yv.x + yv.y * yv.y + yv.z * yv.z + yv.w * yv.w;
    ushort4 xq, yq;
    xq.x = f2bf(xv.x); xq.y = f2bf(xv.y); xq.z = f2bf(xv.z); xq.w = f2bf(xv.w);
    yq.x = f2bf(yv.x); yq.y = f2bf(yv.y); yq.z = f2bf(yv.z); yq.w = f2bf(yv.w);
    sxy += bf2f(xq.x) * bf2f(yq.x) + bf2f(xq.y) * bf2f(yq.y) +
           bf2f(xq.z) * bf2f(yq.z) + bf2f(xq.w) * bf2f(yq.w);
    *reinterpret_cast<ushort4*>(xo + k) = xq;
    *reinterpret_cast<ushort4*>(yo + k) = yq;
  }
#pragma unroll
  for (int off = 32; off > 0; off >>= 1) {
    sxx += __shfl_down(sxx, off);
    syy += __shfl_down(syy, off);
    sxy += __shfl_down(sxy, off);
  }
  if (lane == 0) {
    xn[row] = sxx;
    yn[row] = syy;
    posv[row] = sqrtf(fmaxf(sxx + syy - 2.f * sxy, 0.f));
  }
}

// ---------------- GEMM: 256x256 tile, BK=64, 8 waves, phase pipeline ------
// LDS 128KB: A[dbuf][half] at (d*2+h)*8192, B at 32768+(d*2+h)*8192 (ushorts)
// Phase = output quadrant (qm,qn); qm selects A-half, qn selects B-half.
// Stage order per tile t->t+1: phi0:A0 phi1:B0 phi2:B1 phi3:A1.
// vmcnt ledger (2 loads/thread/half): steady vmcnt(6)@phi0-2, none @phi3;
// last tile drains 4->2->0.

#define VMW(N) asm volatile("s_waitcnt vmcnt(" #N ")" ::: "memory")

#define STAGE(srcbase, ldsb)                                          \
  {                                                                   \
    _Pragma("unroll") for (int c = 0; c < 2; ++c) {                   \
      int L = tid + c * 512;                                          \
      int row_ = L >> 3;                                              \
      int ch_ = (L & 7) ^ (row_ & 7);                                 \
      gload_lds16((srcbase) + (size_t)row_ * DDIM + ch_ * 8,          \
                  (ldsb) + ((w * 64 + c * 512) << 3));                \
    }                                                                 \
  }

#define LOADA(qm, d)                                                  \
  {                                                                   \
    _Pragma("unroll") for (int mm = 0; mm < 4; ++mm)                  \
        _Pragma("unroll") for (int ks = 0; ks < 2; ++ks) {            \
      int rh = wr * 64 + mm * 16 + (lane & 15);                       \
      int ch = (ks * 4 + (lane >> 4)) ^ (rh & 7);                     \
      a[mm][ks] = *reinterpret_cast<const short8v*>(                  \
          smem + ((d) * 2 + (qm)) * 8192 + rh * 64 + ch * 8);         \
    }                                                                 \
  }

#define LOADB(dst, qn, d)                                             \
  {                                                                   \
    _Pragma("unroll") for (int nn = 0; nn < 2; ++nn)                  \
        _Pragma("unroll") for (int ks = 0; ks < 2; ++ks) {            \
      int rh = wc * 32 + nn * 16 + (lane & 15);                       \
      int ch = (ks * 4 + (lane >> 4)) ^ (rh & 7);                     \
      dst[nn][ks] = *reinterpret_cast<const short8v*>(                \
          smem + 32768 + ((d) * 2 + (qn)) * 8192 + rh * 64 + ch * 8); \
    }                                                                 \
  }

#define MFMAQ(qm, qn, bsrc)                                           \
  {                                                                   \
    __builtin_amdgcn_s_setprio(1);                                    \
    _Pragma("unroll") for (int mm = 0; mm < 4; ++mm)                  \
        _Pragma("unroll") for (int nn = 0; nn < 2; ++nn)              \
            _Pragma("unroll") for (int ks = 0; ks < 2; ++ks) {        \
      acc[qm][qn][mm][nn] = __builtin_amdgcn_mfma_f32_16x16x32_bf16(  \
          a[mm][ks], bsrc[nn][ks], acc[qm][qn][mm][nn], 0, 0, 0);     \
    }                                                                 \
    __builtin_amdgcn_s_setprio(0);                                    \
  }

#define BAR()                      \
  __builtin_amdgcn_s_barrier();    \
  __builtin_amdgcn_sched_barrier(0)

__global__ __launch_bounds__(512, 2) void gemm_dist_kernel(
    const unsigned short* __restrict__ Xb, const unsigned short* __restrict__ Yb,
    const float* __restrict__ xn, const float* __restrict__ yn,
    unsigned short* __restrict__ dist, unsigned short* __restrict__ distT) {
  __shared__ unsigned short smem[65536];  // 128 KB

  int tid = threadIdx.x;
  int lane = tid & 63, w = tid >> 6;
  int wr = w >> 2, wc = w & 3;
  // XCD-aware swizzle over 256 blocks (16x16 tile grid), bijective
  int wg = blockIdx.x;
  int swz = (wg & 7) * 32 + (wg >> 3);
  int brow = (swz >> 4) * 256, bcol = (swz & 15) * 256;

  float4v acc[2][2][4][2];
#pragma unroll
  for (int i = 0; i < 2; ++i)
#pragma unroll
    for (int j = 0; j < 2; ++j)
#pragma unroll
      for (int m = 0; m < 4; ++m)
#pragma unroll
        for (int n = 0; n < 2; ++n) acc[i][j][m][n] = (float4v){0.f, 0.f, 0.f, 0.f};

  short8v a[4][2], b0[2][2], b1[2][2];

  // prologue: stage tile 0 halves in ledger order A0,B0,B1,A1 -> dbuf 0
  STAGE(Xb + (size_t)brow * DDIM, smem);
  STAGE(Yb + (size_t)bcol * DDIM, smem + 32768);
  STAGE(Yb + (size_t)(bcol + 128) * DDIM, smem + 32768 + 8192);
  STAGE(Xb + (size_t)(brow + 128) * DDIM, smem + 8192);

  for (int t = 0; t < NT; ++t) {
    int d = t & 1, dn = d ^ 1;
    const unsigned short* xsrc = Xb + (size_t)brow * DDIM + (t + 1) * 64;
    const unsigned short* ysrc = Yb + (size_t)bcol * DDIM + (t + 1) * 64;
    // ---- phase 0: quadrant (0,0); stage A0(t+1)
    if (t < NT - 1) {
      STAGE(xsrc, smem + (dn * 2) * 8192);
      VMW(6);
    } else {
      VMW(4);
    }
    BAR();
    LOADA(0, d);
    LOADB(b0, 0, d);
    MFMAQ(0, 0, b0);
    // ---- phase 1: quadrant (0,1); stage B0(t+1)
    if (t < NT - 1) {
      STAGE(ysrc, smem + 32768 + (dn * 2) * 8192);
      VMW(6);
    } else {
      VMW(2);
    }
    BAR();
    LOADB(b1, 1, d);
    MFMAQ(0, 1, b1);
    // ---- phase 2: quadrant (1,0); stage B1(t+1)
    if (t < NT - 1) {
      STAGE(ysrc + (size_t)128 * DDIM, smem + 32768 + (dn * 2 + 1) * 8192);
      VMW(6);
    } else {
      VMW(0);
    }
    BAR();
    LOADA(1, d);
    MFMAQ(1, 0, b0);
    // ---- phase 3: quadrant (1,1); stage A1(t+1); no vmcnt needed
    if (t < NT - 1) {
      STAGE(xsrc + (size_t)128 * DDIM, smem + (dn * 2 + 1) * 8192);
    }
    BAR();
    MFMAQ(1, 1, b1);
  }

  __syncthreads();

  // ---- epilogue: dist direct from regs; distT via LDS transpose tile ----
#pragma unroll
  for (int qm = 0; qm < 2; ++qm) {
#pragma unroll
    for (int qn = 0; qn < 2; ++qn) {
#pragma unroll
      for (int mm = 0; mm < 4; ++mm) {
#pragma unroll
        for (int nn = 0; nn < 2; ++nn) {
          int r0 = qm * 128 + wr * 64 + mm * 16 + (lane >> 4) * 4;
          int c = qn * 128 + wc * 32 + nn * 16 + (lane & 15);
          float yv = yn[bcol + c];
          ushort4 st;
          unsigned short* sp = reinterpret_cast<unsigned short*>(&st);
#pragma unroll
          for (int j = 0; j < 4; ++j) {
            float sq = xn[brow + r0 + j] + yv - 2.0f * acc[qm][qn][mm][nn][j];
            sp[j] = f2bf(sqrtf(fmaxf(sq, 0.f)));
            dist[(size_t)(brow + r0 + j) * BDIM + bcol + c] = sp[j];
          }
          int phys = (r0 >> 3) ^ (c & 31);
          *reinterpret_cast<uint2*>(reinterpret_cast<char*>(smem) + c * 512 +
                                    phys * 16 + (r0 & 7) * 2) =
              *reinterpret_cast<uint2*>(&st);
        }
      }
    }
  }
  __syncthreads();
  // distT dump: thread -> (col, r-half), 256B contiguous
  {
    int c = tid >> 1, half = tid & 1;
    unsigned short* gout = distT + (size_t)(bcol + c) * BDIM + brow + half * 128;
#pragma unroll
    for (int i = 0; i < 16; ++i) {
      int rc = half * 16 + i;
      int phys = rc ^ (c & 31);
      uint4 v = *reinterpret_cast<const uint4*>(
          reinterpret_cast<const char*>(smem) + c * 512 + phys * 16);
      *reinterpret_cast<uint4*>(gout + i * 8) = v;
    }
  }
}

// ---------------- per-row exact top-K-smallest hinge sum (bf16 keys) ------
__global__ __launch_bounds__(256, 4) void select_kernel(
    const unsigned short* __restrict__ dist,
    const unsigned short* __restrict__ distT,
    const float* __restrict__ posv,
    float* __restrict__ rxy, float* __restrict__ ryx) {
  int lane = threadIdx.x & 63, w = threadIdx.x >> 6;
  int r = blockIdx.x * 4 + w;           // 0..8191
  int rr = (r < BDIM) ? r : r - BDIM;
  const unsigned short* rowp =
      ((r < BDIM) ? dist : distT) + (size_t)rr * BDIM;
  float pos = posv[rr];

  uint32_t key[64];
  uint32_t kmin = 0xFFFFu, kmax = 0u;
#pragma unroll
  for (int i = 0; i < 8; ++i) {
    int idx0 = i * 512 + lane * 8;
    uint4 v = *reinterpret_cast<const uint4*>(rowp + idx0);
    uint32_t pk[4] = {v.x, v.y, v.z, v.w};
#pragma unroll
    for (int p = 0; p < 4; ++p) {
      uint32_t lo = pk[p] & 0xFFFFu, hi = pk[p] >> 16;
      kmin = min(kmin, min(lo, hi));
      kmax = max(kmax, max(lo, hi));
      int idx = idx0 + p * 2;
      key[i * 8 + p * 2 + 0] = (idx + 0 == rr) ? 0xFFFFu : lo;
      key[i * 8 + p * 2 + 1] = (idx + 1 == rr) ? 0xFFFFu : hi;
    }
  }
#pragma unroll
  for (int off = 32; off > 0; off >>= 1) {
    kmin = min(kmin, (uint32_t)__shfl_xor((int)kmin, off));
    kmax = max(kmax, (uint32_t)__shfl_xor((int)kmax, off));
  }

  uint32_t a = kmin, b = kmax;
  uint32_t T;
  bool found = false;
  while (a < b) {
    uint32_t m = (a + b) >> 1;
    int c = 0;
#pragma unroll
    for (int i = 0; i < 64; ++i) c += __popcll(__ballot(key[i] <= m));
    if (c == KSEL) { T = m; found = true; break; }
    if (c > KSEL) b = m; else a = m + 1;
  }
  if (!found) T = a;

  float Tf = __uint_as_float(T << 16);
  float pm = MARGINF + pos;
  float local = 0.f;
  int cnt_less = 0;
#pragma unroll
  for (int i = 0; i < 64; ++i) {
    uint32_t k = key[i];
    cnt_less += __popcll(__ballot(k < T));
    float d = __uint_as_float(k << 16);
    local += (k < T) ? fmaxf(pm - d, 0.f) : 0.f;
  }
#pragma unroll
  for (int off = 32; off > 0; off >>= 1) local += __shfl_xor(local, off);
  if (lane == 0) {
    float loss = local + (float)(KSEL - cnt_less) * fmaxf(pm - Tf, 0.f);
    if (r < BDIM) rxy[rr] = loss; else ryx[rr] = loss;
  }
}

// ---------------- final reduction ----------------
__global__ void finalize_kernel(const float* __restrict__ rxy,
                                const float* __restrict__ ryx,
                                float* __restrict__ out) {
  const float* src = (blockIdx.x == 0) ? rxy : ryx;
  int tid = threadIdx.x;
  double local = 0.0;
  for (int i = tid; i < BDIM; i += 256) local += (double)src[i];
  int lane = tid & 63, w = tid >> 6;
#pragma unroll
  for (int off = 32; off > 0; off >>= 1) local += __shfl_down(local, off);
  __shared__ double wsd[4];
  if (lane == 0) wsd[w] = local;
  __syncthreads();
  if (tid == 0) {
    double s = wsd[0] + wsd[1] + wsd[2] + wsd[3];
    out[blockIdx.x] = (float)(s / ((double)BDIM * (double)KSEL));
  }
}

// ---------------- launch ----------------
extern "C" void kernel_launch(void* const* d_in, const int* in_sizes, int n_in,
                              void* d_out, int out_size, void* d_ws,
                              size_t ws_size, hipStream_t stream) {
  const float* x = (const float*)d_in[0];
  const float* y = (const float*)d_in[1];
  float* out = (float*)d_out;

  char* ws = (char*)d_ws;
  size_t o = 0;
  auto take = [&](size_t bytes) -> void* {
    void* p = (void*)(ws + o);
    o += (bytes + 255) & ~(size_t)255;
    return p;
  };
  unsigned short* xbf = (unsigned short*)take((size_t)BDIM * DDIM * 2);
  unsigned short* ybf = (unsigned short*)take((size_t)BDIM * DDIM * 2);
  float* xn = (float*)take((size_t)BDIM * 4);
  float* yn = (float*)take((size_t)BDIM * 4);
  float* rxy = (float*)take((size_t)BDIM * 4);
  float* ryx = (float*)take((size_t)BDIM * 4);
  float* posv = (float*)take((size_t)BDIM * 4);
  unsigned short* dist = (unsigned short*)take((size_t)BDIM * BDIM * 2);
  unsigned short* distT = (unsigned short*)take((size_t)BDIM * BDIM * 2);

  prep_kernel<<<BDIM / 4, 256, 0, stream>>>(x, y, xbf, ybf, xn, yn, posv);
  gemm_dist_kernel<<<256, 512, 0, stream>>>(xbf, ybf, xn, yn, dist, distT);
  select_kernel<<<2 * BDIM / 4, 256, 0, stream>>>(dist, distT, posv, rxy, ryx);
  finalize_kernel<<<2, 256, 0, stream>>>(rxy, ryx, out);
}